// Round 19
// baseline (332.816 us; speedup 1.0000x reference)
//
#include <hip/hip_runtime.h>
#include <hip/hip_bf16.h>
#include <math.h>

// Problem constants
#define BB   800
#define CIN  4
#define XLEN 600
#define COUT 320
#define KW   26
#define TT   45
#define HID  160
#define LSTM_N 1280          // 2 dirs * [jg(10) x gate(4) x jl(16)] permuted
#define LSTM_K 320
#define LSTM_M 36000
#define GENE_K 19795
#define GENE_N 320
#define LIN_K 14400
#define LIN_N 925
#define GENE_SPLITS 24
#define LIN_SPLITS 15

// Workspace layout (float units).
#define OFF_H      ((size_t)0)          // [36000][320] ush f16
#define OFF_BP     ((size_t)5760000)    // [1280][320] ush f16
#define OFF_BIAS   ((size_t)5964800)    // [1280] f32
#define OFF_WD     ((size_t)5966080)    // [320][128] ush f16 (conv w per-ch padded)
#define OFF_GENE   ((size_t)15820960)   // [800][320] f32
#define OFF_STATS  ((size_t)16076960)   // [640]
#define OFF_ATTN   ((size_t)16077600)   // [45*800]
#define OFF_HID    ((size_t)16113600)   // [800][925]
#define OFF_SCR    ((size_t)16853600)   // gpart 24x256000=6.14M ; lpart 15x740000=11.1M
                                        // (lpart extends over dead seqs region)
#define OFF_SEQS   ((size_t)22997600)   // [36000][320] ush f16 (dead after LSTM GEMM)
// total 28,757,600 f32 = 115.0 MB

typedef __attribute__((ext_vector_type(8))) _Float16 half8v;
typedef __attribute__((ext_vector_type(8))) unsigned short ushort8v;
typedef __attribute__((ext_vector_type(4))) float f32x4;
typedef __attribute__((ext_vector_type(4))) unsigned uint4v;

__device__ __forceinline__ float sigf(float x) { return 1.0f / (1.0f + __expf(-x)); }
__device__ __forceinline__ float tanhfast(float x) { return 2.0f / (1.0f + __expf(-2.0f * x)) - 1.0f; }

__device__ __forceinline__ unsigned short f16rne(float f) {
    _Float16 h = (_Float16)f;                 // RNE
    return __builtin_bit_cast(unsigned short, h);
}
__device__ __forceinline__ float f16tof(unsigned short u) {
    return (float)__builtin_bit_cast(_Float16, u);
}

// Read 8 consecutive ushorts at arbitrary (2B) alignment from LDS via two
// aligned b128 reads + funnel shift. off in ushort units. (HW-verified r10/r11.)
__device__ __forceinline__ ushort8v lds_window8(const unsigned short* chbase, int off) {
    const unsigned short* ap = chbase + (off & ~7);
    uint4 A = *reinterpret_cast<const uint4*>(ap);
    uint4 Bv = *reinterpret_cast<const uint4*>(ap + 8);
    int s = off & 7;
    bool hi4 = s >= 4;
    unsigned e0 = hi4 ? A.z : A.x;
    unsigned e1 = hi4 ? A.w : A.y;
    unsigned e2 = hi4 ? Bv.x : A.z;
    unsigned e3 = hi4 ? Bv.y : A.w;
    unsigned e4 = hi4 ? Bv.z : Bv.x;
    unsigned e5 = hi4 ? Bv.w : Bv.y;
    int s2 = s & 3;
    int bsh = s2 * 16;
    unsigned o0 = (unsigned)((((unsigned long long)e1 << 32) | e0) >> bsh);
    unsigned o1 = (unsigned)((((unsigned long long)e2 << 32) | e1) >> bsh);
    unsigned o2 = (unsigned)((((unsigned long long)e3 << 32) | e2) >> bsh);
    unsigned o3 = (unsigned)((((unsigned long long)e4 << 32) | e3) >> bsh);
    if (s2 == 3) {
        o0 |= e2 << 16;
        o1 |= e3 << 16;
        o2 |= e4 << 16;
        o3 |= e5 << 16;
    }
    uint4v o = {o0, o1, o2, o3};
    return *reinterpret_cast<ushort8v*>(&o);
}

// ---------------------------------------------------------------------------
// Prep kernels (LSTM permute + conv pad only)
// ---------------------------------------------------------------------------
__global__ void prep_lstm_kernel(const float* __restrict__ wf, const float* __restrict__ bif,
                                 const float* __restrict__ bhf,
                                 const float* __restrict__ wb, const float* __restrict__ bib,
                                 const float* __restrict__ bhb,
                                 unsigned short* __restrict__ Bp, float* __restrict__ biasv) {
    int idx = blockIdx.x * 256 + threadIdx.x;
    if (idx < LSTM_N * LSTM_K) {
        int n = idx / LSTM_K, k = idx % LSTM_K;
        int dir = n / 640, r = n % 640;
        int jg = r >> 6, rr = r & 63, gate = rr >> 4, jl = rr & 15;
        int srow = gate * HID + jg * 16 + jl;
        const float* w = dir ? wb : wf;
        Bp[idx] = f16rne(w[(size_t)srow * LSTM_K + k]);
    }
    if (idx < LSTM_N) {
        int n = idx;
        int dir = n / 640, r = n % 640;
        int jg = r >> 6, rr = r & 63, gate = rr >> 4, jl = rr & 15;
        int srow = gate * HID + jg * 16 + jl;
        biasv[n] = dir ? (bib[srow] + bhb[srow]) : (bif[srow] + bhf[srow]);
    }
}

// Conv weights: per-channel padded layout k = ch*32 + kk (kk<26 valid, else 0)
__global__ void prep_convw_kernel(const float* __restrict__ cw, unsigned short* __restrict__ wd) {
    int idx = blockIdx.x * 256 + threadIdx.x;
    if (idx < COUT * 128) {
        int c = idx >> 7, k = idx & 127;
        int ch = k >> 5, kk = k & 31;
        wd[idx] = (kk < KW) ? f16rne(cw[(size_t)c * 104 + ch * KW + kk]) : (unsigned short)0;
    }
}

// ---------------------------------------------------------------------------
// Fused Conv1d + bias + ReLU + pad + MaxPool via MFMA (r12/r14-proven:
// two-phase f32 half-tile Csh epilogue, no spill). LDS 36KB -> 4 blocks/CU.
// ---------------------------------------------------------------------------
#define AST 136
#define CST 130

__global__ __launch_bounds__(256, 4) void conv_mfma_kernel(const float* __restrict__ x,
                                                           const unsigned short* __restrict__ wd,
                                                           const float* __restrict__ cb,
                                                           unsigned short* __restrict__ seqs) {
    __shared__ __align__(16) unsigned char smem[36096];
    unsigned short* As = (unsigned short*)smem;              // [128][AST]
    unsigned short* xraw = As + 128 * AST;                   // [4][160]
    float* Csh = (float*)smem;                               // [64][CST] f32, aliases As

    int bx = blockIdx.x;
    int b = bx / 5, wt = bx % 5;
    int col0 = blockIdx.y * 128;
    int p0 = 117 * wt - 14;
    int tid = threadIdx.x;

    const int w = tid >> 6, lane = tid & 63;
    const int wr = w >> 1, wc = w & 1;
    const int l15 = lane & 15, lq = lane >> 4;

    ushort8v bA[4], bB[4];
#pragma unroll
    for (int n = 0; n < 4; ++n) {
        int cg = col0 + wc * 64 + n * 16 + l15;
        cg = min(cg, COUT - 1);
        bA[n] = *reinterpret_cast<const ushort8v*>(wd + (size_t)cg * 128 + 0 * 32 + lq * 8);
    }

    // 1. stage raw x window (f16 RNE)
    {
        const float* xb = x + (size_t)b * (CIN * XLEN);
        if (wt >= 1 && wt <= 3) {
            for (int j = tid; j < 4 * 160; j += 256) {
                int ch = j / 160, i = j - ch * 160;
                float v = (i < 154) ? xb[ch * XLEN + p0 + i] : 0.0f;
                xraw[ch * 160 + i] = f16rne(v);
            }
        } else {
            for (int j = tid; j < 4 * 160; j += 256) {
                int ch = j / 160, i = j - ch * 160;
                int p = p0 + i;
                float v = (i < 154 && p >= 0 && p < XLEN) ? xb[ch * XLEN + p] : 0.0f;
                xraw[ch * 160 + i] = f16rne(v);
            }
        }
    }
    __syncthreads();

    // 2. im2col via aligned b128 + funnel windows; k = ch*32+kk
#pragma unroll
    for (int i = 0; i < 8; ++i) {
        int j = i * 256 + tid;
        int r = j >> 4, kg = j & 15;
        int ch = kg >> 2, q = kg & 3;
        const unsigned short* chb = xraw + ch * 160;
        ushort8v o;
        if (q < 3) {
            o = lds_window8(chb, r + q * 8);
        } else {
            o = (ushort8v){chb[r + 24], chb[r + 25], 0, 0, 0, 0, 0, 0};
        }
        *reinterpret_cast<ushort8v*>(As + r * AST + kg * 8) = o;
    }
    __syncthreads();

    // 3. MFMA: 4 k-steps, B ping-pong prefetch
    f32x4 acc[4][4];
#pragma unroll
    for (int m = 0; m < 4; ++m)
#pragma unroll
        for (int n = 0; n < 4; ++n) acc[m][n] = (f32x4){0.f, 0.f, 0.f, 0.f};

#pragma unroll
    for (int ks = 0; ks < 4; ++ks) {
        const ushort8v* bcur = (ks & 1) ? bB : bA;
        ushort8v* bnext = (ks & 1) ? bA : bB;
        if (ks < 3) {
#pragma unroll
            for (int n = 0; n < 4; ++n) {
                int cg = col0 + wc * 64 + n * 16 + l15;
                cg = min(cg, COUT - 1);
                bnext[n] = *reinterpret_cast<const ushort8v*>(
                    wd + (size_t)cg * 128 + (ks + 1) * 32 + lq * 8);
            }
        }
        half8v af[4];
#pragma unroll
        for (int m = 0; m < 4; ++m)
            af[m] = *reinterpret_cast<const half8v*>(As + (wr * 64 + m * 16 + l15) * AST + ks * 32 + lq * 8);
#pragma unroll
        for (int m = 0; m < 4; ++m)
#pragma unroll
            for (int n = 0; n < 4; ++n)
                acc[m][n] = __builtin_amdgcn_mfma_f32_16x16x32_f16(
                    af[m], *reinterpret_cast<const half8v*>(&bcur[n]), acc[m][n], 0, 0, 0);
    }
    __syncthreads();   // As dead; Csh aliases it

    float pu4 = -1.0e30f;

    // 4a. wr=0 waves write C rows 0..63
    if (wr == 0) {
#pragma unroll
        for (int m = 0; m < 4; ++m)
#pragma unroll
            for (int n = 0; n < 4; ++n)
#pragma unroll
                for (int rg = 0; rg < 4; ++rg) {
                    int row = m * 16 + lq * 4 + rg;
                    int col = wc * 64 + n * 16 + l15;
                    Csh[row * CST + col] = acc[m][n][rg];
                }
    }
    __syncthreads();

    // 4b. pool u=0..3 + partial u=4
#pragma unroll
    for (int i = 0; i < 2; ++i) {
        int j = i * 256 + tid;
        int u = j >> 7, c = j & 127;
        int cg = col0 + c;
        float mx = -1.0e30f;
        if (wt == 0) {
#pragma unroll
            for (int jj = 0; jj < 13; ++jj) {
                int r = 13 * u + jj;
                if (r >= 14) mx = fmaxf(mx, Csh[r * CST + c]);
            }
        } else {
#pragma unroll
            for (int jj = 0; jj < 13; ++jj) {
                int r = 13 * u + jj;
                mx = fmaxf(mx, Csh[r * CST + c]);
            }
        }
        if (cg < COUT) {
            float v = fmaxf(mx + cb[cg], 0.0f);
            seqs[((size_t)(wt * 9 + u) * BB + b) * 320 + cg] = f16rne(v);
        }
    }
    if (tid < 128) {
        int c = tid;
#pragma unroll
        for (int jj = 0; jj < 12; ++jj) pu4 = fmaxf(pu4, Csh[(52 + jj) * CST + c]);
    }
    __syncthreads();

    // 5a. wr=1 waves write C rows 64..127
    if (wr == 1) {
#pragma unroll
        for (int m = 0; m < 4; ++m)
#pragma unroll
            for (int n = 0; n < 4; ++n)
#pragma unroll
                for (int rg = 0; rg < 4; ++rg) {
                    int row = m * 16 + lq * 4 + rg;
                    int col = wc * 64 + n * 16 + l15;
                    Csh[row * CST + col] = acc[m][n][rg];
                }
    }
    __syncthreads();

    // 5b. pool u=5..8 + finish u=4
#pragma unroll
    for (int i = 0; i < 2; ++i) {
        int j = i * 256 + tid;
        int u = 5 + (j >> 7), c = j & 127;
        int cg = col0 + c;
        float mx = -1.0e30f;
#pragma unroll
        for (int jj = 0; jj < 13; ++jj) {
            int r = 13 * u + jj;
            mx = fmaxf(mx, Csh[(r - 64) * CST + c]);
        }
        if (cg < COUT) {
            float v = fmaxf(mx + cb[cg], 0.0f);
            seqs[((size_t)(wt * 9 + u) * BB + b) * 320 + cg] = f16rne(v);
        }
    }
    if (tid < 128) {
        int c = tid;
        int cg = col0 + c;
        pu4 = fmaxf(pu4, Csh[0 * CST + c]);
        if (cg < COUT) {
            float v = fmaxf(pu4 + cb[cg], 0.0f);
            seqs[((size_t)(wt * 9 + 4) * BB + b) * 320 + cg] = f16rne(v);
        }
    }
}

// ---------------------------------------------------------------------------
// gemm2: single-pass f16 GEMM. out[r][n] = sum_k f16(A[r][k]) * f16(B[n][k]).
// BF32: B loaded as f32 from global, converted f16 during staging.
// VAR 0 = LSTM (A = seqs f16, epilogue -> h f16, XCD grid; B pre-permuted f16)
// VAR 1 = gene (A f32 -> f16; B = gene_w f32, split-K 24, XCD-pinned sp)
// VAR 2 = lin  (A = attn*h f16; B = lin_w f32, split-K 15)
// ---------------------------------------------------------------------------
template <int VAR, bool BF32>
__global__ __launch_bounds__(256) void gemm2(const unsigned short* __restrict__ Apre,
                                             const float* __restrict__ Af32, int lda,
                                             const unsigned short* __restrict__ Bn,
                                             const float* __restrict__ Bf32, int ldb,
                                             const float* __restrict__ attnp,
                                             int M, int N, int Kreal,
                                             int totChunks, int cps,
                                             float* __restrict__ outp,
                                             const float* __restrict__ biasv,
                                             unsigned short* __restrict__ hout) {
    __shared__ unsigned short Al[128][72];
    __shared__ unsigned short Bl[128][72];
    const int tid = threadIdx.x;

    int bm, bn, sp;
    if (VAR == 0) {
        int xcd = blockIdx.x;
        bn = blockIdx.y % 10;
        bm = xcd + 8 * (blockIdx.y / 10);
        sp = 0;
        if (bm >= 282) return;
    } else if (VAR == 1) {
        int xcd = blockIdx.x;
        sp = xcd + 8 * (blockIdx.y / 21);
        int r = blockIdx.y % 21;
        bm = r / 3; bn = r % 3;
    } else {
        sp = blockIdx.x;
        bn = blockIdx.y / 7; bm = blockIdx.y % 7;
    }
    const int row0 = bm * 128, col0 = bn * 128;
    const int c_beg = sp * cps;
    const int c_end = min(totChunks, c_beg + cps);

    const int w = tid >> 6, lane = tid & 63;
    const int wr = w >> 1, wc = w & 1;
    const int l15 = lane & 15, lq = lane >> 4;

    f32x4 acc[4][4];
#pragma unroll
    for (int m = 0; m < 4; ++m)
#pragma unroll
        for (int n = 0; n < 4; ++n) acc[m][n] = (f32x4){0.f, 0.f, 0.f, 0.f};

    ushort8v aP[4];      // VAR0 raw seqs, VAR2 raw h
    float4 aF[8];        // VAR1 raw f32
    float aW[4];         // VAR2 attn weights
    ushort8v bP[4];      // !BF32
    float4 bF[8];        // BF32 raw f32

    auto loadA = [&](int c) {
        int k0 = c * 64;
        if (VAR == 0) {
#pragma unroll
            for (int i = 0; i < 4; ++i) {
                int j = tid + i * 256;
                int r = j >> 3, kg = j & 7;
                int gr = row0 + r;
                ushort8v z = {0, 0, 0, 0, 0, 0, 0, 0};
                if (gr < M) z = *reinterpret_cast<const ushort8v*>(
                    Apre + (size_t)gr * 320 + k0 + kg * 8);
                aP[i] = z;
            }
        } else if (VAR == 1) {
            bool fast = (k0 + 64 <= Kreal);
#pragma unroll
            for (int i = 0; i < 4; ++i) {
                int j = tid + i * 256;
                int r = j >> 3, kg = j & 7;
                int gr = row0 + r;
                float4 v0 = make_float4(0.f, 0.f, 0.f, 0.f);
                float4 v1 = make_float4(0.f, 0.f, 0.f, 0.f);
                if (gr < M) {
                    int kb = k0 + kg * 8;
                    const float* p = Af32 + (size_t)gr * lda + kb;
                    if (fast) {
                        v0 = *reinterpret_cast<const float4*>(p);
                        v1 = *reinterpret_cast<const float4*>(p + 4);
                    } else {
                        if (kb + 0 < Kreal) v0.x = p[0];
                        if (kb + 1 < Kreal) v0.y = p[1];
                        if (kb + 2 < Kreal) v0.z = p[2];
                        if (kb + 3 < Kreal) v0.w = p[3];
                        if (kb + 4 < Kreal) v1.x = p[4];
                        if (kb + 5 < Kreal) v1.y = p[5];
                        if (kb + 6 < Kreal) v1.z = p[6];
                        if (kb + 7 < Kreal) v1.w = p[7];
                    }
                }
                aF[2 * i] = v0; aF[2 * i + 1] = v1;
            }
        } else {
            int t = k0 / 320, d0 = k0 - t * 320;
#pragma unroll
            for (int i = 0; i < 4; ++i) {
                int j = tid + i * 256;
                int r = j >> 3, kg = j & 7;
                int gr = row0 + r;
                ushort8v z = {0, 0, 0, 0, 0, 0, 0, 0};
                float aw = 0.0f;
                if (gr < M) {
                    z = *reinterpret_cast<const ushort8v*>(
                        Apre + ((size_t)t * BB + gr) * 320 + d0 + kg * 8);
                    aw = attnp[t * BB + gr];
                }
                aP[i] = z; aW[i] = aw;
            }
        }
    };
    auto loadB = [&](int c) {
        int k0 = c * 64;
        if (BF32) {
            bool fast = (k0 + 64 <= Kreal);
#pragma unroll
            for (int i = 0; i < 4; ++i) {
                int j = tid + i * 256;
                int r = j >> 3, kg = j & 7;
                int gc = col0 + r;
                float4 v0 = make_float4(0.f, 0.f, 0.f, 0.f);
                float4 v1 = make_float4(0.f, 0.f, 0.f, 0.f);
                if (gc < N) {
                    int kb = k0 + kg * 8;
                    const float* p = Bf32 + (size_t)gc * ldb + kb;
                    if (fast) {
                        v0 = *reinterpret_cast<const float4*>(p);
                        v1 = *reinterpret_cast<const float4*>(p + 4);
                    } else {
                        if (kb + 0 < Kreal) v0.x = p[0];
                        if (kb + 1 < Kreal) v0.y = p[1];
                        if (kb + 2 < Kreal) v0.z = p[2];
                        if (kb + 3 < Kreal) v0.w = p[3];
                        if (kb + 4 < Kreal) v1.x = p[4];
                        if (kb + 5 < Kreal) v1.y = p[5];
                        if (kb + 6 < Kreal) v1.z = p[6];
                        if (kb + 7 < Kreal) v1.w = p[7];
                    }
                }
                bF[2 * i] = v0; bF[2 * i + 1] = v1;
            }
        } else {
#pragma unroll
            for (int i = 0; i < 4; ++i) {
                int j = tid + i * 256;
                int r = j >> 3, sg = j & 7;
                int gc = col0 + r;
                ushort8v z = {0, 0, 0, 0, 0, 0, 0, 0};
                if (gc < N) z = *reinterpret_cast<const ushort8v*>(Bn + (size_t)gc * ldb + k0 + sg * 8);
                bP[i] = z;
            }
        }
    };
    auto writeAB = [&]() {
        if (VAR == 0) {
#pragma unroll
            for (int i = 0; i < 4; ++i) {
                int j = tid + i * 256;
                int r = j >> 3, kg = j & 7;
                *reinterpret_cast<ushort8v*>(&Al[r][kg * 8]) = aP[i];
            }
        } else {
#pragma unroll
            for (int i = 0; i < 4; ++i) {
                int j = tid + i * 256;
                int r = j >> 3, kg = j & 7;
                ushort8v hv;
                if (VAR == 1) {
                    hv[0] = f16rne(aF[2 * i].x); hv[1] = f16rne(aF[2 * i].y);
                    hv[2] = f16rne(aF[2 * i].z); hv[3] = f16rne(aF[2 * i].w);
                    hv[4] = f16rne(aF[2 * i + 1].x); hv[5] = f16rne(aF[2 * i + 1].y);
                    hv[6] = f16rne(aF[2 * i + 1].z); hv[7] = f16rne(aF[2 * i + 1].w);
                } else {
#pragma unroll
                    for (int e = 0; e < 8; ++e) hv[e] = f16rne(f16tof(aP[i][e]) * aW[i]);
                }
                *reinterpret_cast<ushort8v*>(&Al[r][kg * 8]) = hv;
            }
        }
        if (BF32) {
#pragma unroll
            for (int i = 0; i < 4; ++i) {
                int j = tid + i * 256;
                int r = j >> 3, kg = j & 7;
                ushort8v hv;
                hv[0] = f16rne(bF[2 * i].x); hv[1] = f16rne(bF[2 * i].y);
                hv[2] = f16rne(bF[2 * i].z); hv[3] = f16rne(bF[2 * i].w);
                hv[4] = f16rne(bF[2 * i + 1].x); hv[5] = f16rne(bF[2 * i + 1].y);
                hv[6] = f16rne(bF[2 * i + 1].z); hv[7] = f16rne(bF[2 * i + 1].w);
                *reinterpret_cast<ushort8v*>(&Bl[r][kg * 8]) = hv;
            }
        } else {
#pragma unroll
            for (int i = 0; i < 4; ++i) {
                int j = tid + i * 256;
                int r = j >> 3, sg = j & 7;
                *reinterpret_cast<ushort8v*>(&Bl[r][sg * 8]) = bP[i];
            }
        }
    };

    loadA(c_beg); loadB(c_beg);

    for (int c = c_beg; c < c_end; ++c) {
        __syncthreads();
        writeAB();
        __syncthreads();
        if (c + 1 < c_end) { loadA(c + 1); loadB(c + 1); }

#pragma unroll
        for (int ks = 0; ks < 2; ++ks) {
            half8v bf[4];
#pragma unroll
            for (int n = 0; n < 4; ++n)
                bf[n] = *reinterpret_cast<const half8v*>(&Bl[wc * 64 + n * 16 + l15][ks * 32 + lq * 8]);
            half8v af[4];
#pragma unroll
            for (int m = 0; m < 4; ++m)
                af[m] = *reinterpret_cast<const half8v*>(&Al[wr * 64 + m * 16 + l15][ks * 32 + lq * 8]);
#pragma unroll
            for (int m = 0; m < 4; ++m)
#pragma unroll
                for (int n = 0; n < 4; ++n)
                    acc[m][n] = __builtin_amdgcn_mfma_f32_16x16x32_f16(af[m], bf[n], acc[m][n], 0, 0, 0);
        }
    }

    if (VAR != 0) {
#pragma unroll
        for (int m = 0; m < 4; ++m)
#pragma unroll
            for (int n = 0; n < 4; ++n)
#pragma unroll
                for (int rg = 0; rg < 4; ++rg) {
                    int row_g = row0 + wr * 64 + m * 16 + lq * 4 + rg;
                    int col_g = col0 + wc * 64 + n * 16 + l15;
                    if (row_g < M && col_g < N)
                        outp[((size_t)sp * M + row_g) * N + col_g] = acc[m][n][rg];
                }
    } else {
        int c0 = col0 + wc * 64;
        int dir = c0 / 640;
        int jgl = (c0 % 640) >> 6;
        int hcol = dir * HID + jgl * 16 + l15;
        float bi = biasv[c0 + l15];
        float bg = biasv[c0 + 32 + l15];
        float bo = biasv[c0 + 48 + l15];
#pragma unroll
        for (int m = 0; m < 4; ++m)
#pragma unroll
            for (int rg = 0; rg < 4; ++rg) {
                int row_g = row0 + wr * 64 + m * 16 + lq * 4 + rg;
                if (row_g >= M) continue;
                float gi = acc[m][0][rg] + bi;
                float gg = acc[m][2][rg] + bg;
                float go = acc[m][3][rg] + bo;
                float cc = sigf(gi) * tanhfast(gg);
                hout[(size_t)row_g * 320 + hcol] = f16rne(sigf(go) * tanhfast(cc));
            }
    }
}

// ---------------------------------------------------------------------------
__global__ void gene_reduce_kernel(const float* __restrict__ part, const float* __restrict__ gene_b,
                                   float* __restrict__ out) {
    int idx = blockIdx.x * 256 + threadIdx.x;
    if (idx >= BB * GENE_N) return;
    int n = idx % GENE_N;
    float sum = gene_b[n];
#pragma unroll
    for (int ss = 0; ss < GENE_SPLITS; ++ss) sum += part[(size_t)ss * (BB * GENE_N) + idx];
    out[idx] = sum;
}

__global__ void bn_stats_kernel(const float* __restrict__ g, float* __restrict__ stats) {
    int n = blockIdx.x;
    int tid = threadIdx.x;
    float s = 0.0f, s2 = 0.0f;
    for (int m = tid; m < BB; m += 256) {
        float v = g[(size_t)m * GENE_N + n];
        s += v; s2 += v * v;
    }
    __shared__ float red0[256], red1[256];
    red0[tid] = s; red1[tid] = s2;
    __syncthreads();
    for (int off = 128; off; off >>= 1) {
        if (tid < off) { red0[tid] += red0[tid + off]; red1[tid] += red1[tid + off]; }
        __syncthreads();
    }
    if (tid == 0) {
        float mean = red0[0] / (float)BB;
        float var = red1[0] / (float)BB - mean * mean;
        stats[n] = mean;
        stats[GENE_N + n] = rsqrtf(var + 1e-5f);
    }
}

// attn with BN-normalize + ReLU fused; 4 rows per 256-thread block.
__global__ void attn_kernel(const unsigned short* __restrict__ h, const float* __restrict__ graw,
                            const float* __restrict__ stats,
                            const float* __restrict__ gamma, const float* __restrict__ beta,
                            float* __restrict__ attn) {
    int r = blockIdx.x * 4 + (threadIdx.x >> 6);
    int b = r % BB;
    int lane = threadIdx.x & 63;
    const unsigned short* hr = h + (size_t)r * 320;
    const float* gr = graw + (size_t)b * 320;
    float s = 0.0f;
    for (int d = lane; d < 320; d += 64) {
        float gv = (gr[d] - stats[d]) * stats[GENE_N + d] * gamma[d] + beta[d];
        gv = fmaxf(gv, 0.0f);
        s += f16tof(hr[d]) * gv;
    }
    for (int off = 32; off; off >>= 1) s += __shfl_down(s, off);
    if (lane == 0) attn[r] = s;
}

__global__ void lin_reduce_kernel(const float* __restrict__ part, const float* __restrict__ lin_b,
                                  float* __restrict__ hid) {
    int idx = blockIdx.x * 256 + threadIdx.x;
    if (idx >= BB * LIN_N) return;
    int n = idx % LIN_N;
    float sum = lin_b[n];
#pragma unroll
    for (int ss = 0; ss < LIN_SPLITS; ++ss) sum += part[(size_t)ss * (BB * LIN_N) + idx];
    hid[idx] = fmaxf(sum, 0.0f);
}

__global__ void out_kernel(const float* __restrict__ hid, const float* __restrict__ ow,
                           const float* __restrict__ ob, float* __restrict__ out) {
    int b = blockIdx.x;
    int lane = threadIdx.x;
    float s = 0.0f;
    for (int n = lane; n < LIN_N; n += 64) s += hid[(size_t)b * LIN_N + n] * ow[n];
    for (int off = 32; off; off >>= 1) s += __shfl_down(s, off);
    if (lane == 0) out[b] = s + ob[0];
}

// ---------------------------------------------------------------------------
extern "C" void kernel_launch(void* const* d_in, const int* in_sizes, int n_in,
                              void* d_out, int out_size, void* d_ws, size_t ws_size,
                              hipStream_t stream) {
    const float* x        = (const float*)d_in[0];
    const float* geneexpr = (const float*)d_in[1];
    const float* conv_w   = (const float*)d_in[2];
    const float* conv_b   = (const float*)d_in[3];
    const float* w_ih_f   = (const float*)d_in[4];
    const float* b_ih_f   = (const float*)d_in[5];
    const float* b_hh_f   = (const float*)d_in[6];
    const float* w_ih_b   = (const float*)d_in[7];
    const float* b_ih_b   = (const float*)d_in[8];
    const float* b_hh_b   = (const float*)d_in[9];
    const float* gene_w   = (const float*)d_in[10];
    const float* gene_b   = (const float*)d_in[11];
    const float* bn_gamma = (const float*)d_in[12];
    const float* bn_beta  = (const float*)d_in[13];
    const float* lin_w    = (const float*)d_in[14];
    const float* lin_b    = (const float*)d_in[15];
    const float* out_w    = (const float*)d_in[16];
    const float* out_b    = (const float*)d_in[17];

    float* ws  = (float*)d_ws;
    float* out = (float*)d_out;

    unsigned short* h     = (unsigned short*)(ws + OFF_H);
    unsigned short* Bp    = (unsigned short*)(ws + OFF_BP);
    float* biasv          = ws + OFF_BIAS;
    unsigned short* wd    = (unsigned short*)(ws + OFF_WD);
    float* gene           = ws + OFF_GENE;
    float* stats          = ws + OFF_STATS;
    float* attn           = ws + OFF_ATTN;
    float* hid            = ws + OFF_HID;
    float* gpart          = ws + OFF_SCR;
    float* lpart          = ws + OFF_SCR;   // extends over dead seqs region
    unsigned short* seqs  = (unsigned short*)(ws + OFF_SEQS);

    // 1. weight preps (LSTM permute + conv pad only)
    prep_lstm_kernel<<<1600, 256, 0, stream>>>(w_ih_f, b_ih_f, b_hh_f,
                                               w_ih_b, b_ih_b, b_hh_b, Bp, biasv);
    prep_convw_kernel<<<160, 256, 0, stream>>>(conv_w, wd);
    // 2. fused conv -> seqs f16
    conv_mfma_kernel<<<dim3(BB * 5, 3, 1), 256, 0, stream>>>(x, wd, conv_b, seqs);
    // 3. LSTM GEMM (XCD-pinned bm) -> h f16
    gemm2<0, false><<<dim3(8, 360), 256, 0, stream>>>(
        seqs, nullptr, 0, Bp, nullptr, LSTM_K, nullptr,
        LSTM_M, LSTM_N, LSTM_K, 5, 5, nullptr, biasv, h);
    // 4. gene GEMM (split-K 24, XCD-pinned sp; B = gene_w f32 direct)
    gemm2<1, true><<<dim3(8, 63), 256, 0, stream>>>(
        nullptr, geneexpr, GENE_K, nullptr, gene_w, GENE_K, nullptr,
        BB, GENE_N, GENE_K, 310, 13, gpart, nullptr, nullptr);
    // 5. reduce + bias
    gene_reduce_kernel<<<1000, 256, 0, stream>>>(gpart, gene_b, gene);
    // 6. BN stats
    bn_stats_kernel<<<GENE_N, 256, 0, stream>>>(gene, stats);
    // 7. attention scores (BN apply fused)
    attn_kernel<<<9000, 256, 0, stream>>>(h, gene, stats, bn_gamma, bn_beta, attn);
    // 8. lin GEMM (split-K 15; A = attn*h, B = lin_w f32 direct)
    gemm2<2, true><<<dim3(LIN_SPLITS, 56), 256, 0, stream>>>(
        h, nullptr, 0, nullptr, lin_w, LIN_K, attn,
        BB, LIN_N, LIN_K, 225, 15, lpart, nullptr, nullptr);
    // 9. reduce + bias + relu
    lin_reduce_kernel<<<2891, 256, 0, stream>>>(lpart, lin_b, hid);
    // 10. final dot
    out_kernel<<<BB, 64, 0, stream>>>(hid, out_w, out_b, out);
}

// Round 20
// 301.348 us; speedup vs baseline: 1.1044x; 1.1044x over previous
//
#include <hip/hip_runtime.h>
#include <hip/hip_bf16.h>
#include <math.h>

// Problem constants
#define BB   800
#define CIN  4
#define XLEN 600
#define COUT 320
#define KW   26
#define TT   45
#define HID  160
#define LSTM_N 1280          // 2 dirs * [jg(10) x gate(4) x jl(16)] permuted
#define LSTM_K 320
#define LSTM_M 36000
#define GENE_K 19795
#define GENE_N 320
#define LIN_K 14400
#define LIN_N 925
#define GENE_SPLITS 24
#define LIN_SPLITS 8

// Workspace layout (float units).
#define OFF_H      ((size_t)0)          // [36000][320] ush f16
#define OFF_BP     ((size_t)5760000)    // [1280][320] ush f16
#define OFF_BIAS   ((size_t)5964800)    // [1280] f32
#define OFF_WD     ((size_t)5966080)    // [320][128] ush f16 (conv w per-ch padded)
#define OFF_GENE   ((size_t)15820960)   // [800][320] f32
#define OFF_STATS  ((size_t)16076960)   // [640]
#define OFF_ATTN   ((size_t)16077600)   // [45*800]
#define OFF_HID    ((size_t)16113600)   // [800][925]
#define OFF_SCR    ((size_t)16853600)   // scratch: gpart 24x256000 / lpart 8x740000
#define OFF_SEQS   ((size_t)22997600)   // [36000][320] ush f16
// total 28,757,600 f32 = 115.0 MB

typedef __attribute__((ext_vector_type(8))) _Float16 half8v;
typedef __attribute__((ext_vector_type(8))) unsigned short ushort8v;
typedef __attribute__((ext_vector_type(4))) float f32x4;
typedef __attribute__((ext_vector_type(4))) unsigned uint4v;

__device__ __forceinline__ float sigf(float x) { return 1.0f / (1.0f + __expf(-x)); }
__device__ __forceinline__ float tanhfast(float x) { return 2.0f / (1.0f + __expf(-2.0f * x)) - 1.0f; }

__device__ __forceinline__ unsigned short f16rne(float f) {
    _Float16 h = (_Float16)f;                 // RNE
    return __builtin_bit_cast(unsigned short, h);
}
__device__ __forceinline__ float f16tof(unsigned short u) {
    return (float)__builtin_bit_cast(_Float16, u);
}

// Read 8 consecutive ushorts at arbitrary (2B) alignment from LDS via two
// aligned b128 reads + funnel shift. off in ushort units. (HW-verified r10/r11.)
__device__ __forceinline__ ushort8v lds_window8(const unsigned short* chbase, int off) {
    const unsigned short* ap = chbase + (off & ~7);
    uint4 A = *reinterpret_cast<const uint4*>(ap);
    uint4 Bv = *reinterpret_cast<const uint4*>(ap + 8);
    int s = off & 7;
    bool hi4 = s >= 4;
    unsigned e0 = hi4 ? A.z : A.x;
    unsigned e1 = hi4 ? A.w : A.y;
    unsigned e2 = hi4 ? Bv.x : A.z;
    unsigned e3 = hi4 ? Bv.y : A.w;
    unsigned e4 = hi4 ? Bv.z : Bv.x;
    unsigned e5 = hi4 ? Bv.w : Bv.y;
    int s2 = s & 3;
    int bsh = s2 * 16;
    unsigned o0 = (unsigned)((((unsigned long long)e1 << 32) | e0) >> bsh);
    unsigned o1 = (unsigned)((((unsigned long long)e2 << 32) | e1) >> bsh);
    unsigned o2 = (unsigned)((((unsigned long long)e3 << 32) | e2) >> bsh);
    unsigned o3 = (unsigned)((((unsigned long long)e4 << 32) | e3) >> bsh);
    if (s2 == 3) {
        o0 |= e2 << 16;
        o1 |= e3 << 16;
        o2 |= e4 << 16;
        o3 |= e5 << 16;
    }
    uint4v o = {o0, o1, o2, o3};
    return *reinterpret_cast<ushort8v*>(&o);
}

// ---------------------------------------------------------------------------
// Prep kernels (LSTM permute + conv pad only)
// ---------------------------------------------------------------------------
__global__ void prep_lstm_kernel(const float* __restrict__ wf, const float* __restrict__ bif,
                                 const float* __restrict__ bhf,
                                 const float* __restrict__ wb, const float* __restrict__ bib,
                                 const float* __restrict__ bhb,
                                 unsigned short* __restrict__ Bp, float* __restrict__ biasv) {
    int idx = blockIdx.x * 256 + threadIdx.x;
    if (idx < LSTM_N * LSTM_K) {
        int n = idx / LSTM_K, k = idx % LSTM_K;
        int dir = n / 640, r = n % 640;
        int jg = r >> 6, rr = r & 63, gate = rr >> 4, jl = rr & 15;
        int srow = gate * HID + jg * 16 + jl;
        const float* w = dir ? wb : wf;
        Bp[idx] = f16rne(w[(size_t)srow * LSTM_K + k]);
    }
    if (idx < LSTM_N) {
        int n = idx;
        int dir = n / 640, r = n % 640;
        int jg = r >> 6, rr = r & 63, gate = rr >> 4, jl = rr & 15;
        int srow = gate * HID + jg * 16 + jl;
        biasv[n] = dir ? (bib[srow] + bhb[srow]) : (bif[srow] + bhf[srow]);
    }
}

// Conv weights: per-channel padded layout k = ch*32 + kk (kk<26 valid, else 0)
__global__ void prep_convw_kernel(const float* __restrict__ cw, unsigned short* __restrict__ wd) {
    int idx = blockIdx.x * 256 + threadIdx.x;
    if (idx < COUT * 128) {
        int c = idx >> 7, k = idx & 127;
        int ch = k >> 5, kk = k & 31;
        wd[idx] = (kk < KW) ? f16rne(cw[(size_t)c * 104 + ch * KW + kk]) : (unsigned short)0;
    }
}

// ---------------------------------------------------------------------------
// Fused Conv1d + bias + ReLU + pad + MaxPool via MFMA (r12/r14-proven:
// two-phase f32 half-tile Csh epilogue, no spill). LDS 36KB -> 4 blocks/CU.
// ---------------------------------------------------------------------------
#define AST 136
#define CST 130

__global__ __launch_bounds__(256, 4) void conv_mfma_kernel(const float* __restrict__ x,
                                                           const unsigned short* __restrict__ wd,
                                                           const float* __restrict__ cb,
                                                           unsigned short* __restrict__ seqs) {
    __shared__ __align__(16) unsigned char smem[36096];
    unsigned short* As = (unsigned short*)smem;              // [128][AST]
    unsigned short* xraw = As + 128 * AST;                   // [4][160]
    float* Csh = (float*)smem;                               // [64][CST] f32, aliases As

    int bx = blockIdx.x;
    int b = bx / 5, wt = bx % 5;
    int col0 = blockIdx.y * 128;
    int p0 = 117 * wt - 14;
    int tid = threadIdx.x;

    const int w = tid >> 6, lane = tid & 63;
    const int wr = w >> 1, wc = w & 1;
    const int l15 = lane & 15, lq = lane >> 4;

    ushort8v bA[4], bB[4];
#pragma unroll
    for (int n = 0; n < 4; ++n) {
        int cg = col0 + wc * 64 + n * 16 + l15;
        cg = min(cg, COUT - 1);
        bA[n] = *reinterpret_cast<const ushort8v*>(wd + (size_t)cg * 128 + 0 * 32 + lq * 8);
    }

    // 1. stage raw x window (f16 RNE)
    {
        const float* xb = x + (size_t)b * (CIN * XLEN);
        if (wt >= 1 && wt <= 3) {
            for (int j = tid; j < 4 * 160; j += 256) {
                int ch = j / 160, i = j - ch * 160;
                float v = (i < 154) ? xb[ch * XLEN + p0 + i] : 0.0f;
                xraw[ch * 160 + i] = f16rne(v);
            }
        } else {
            for (int j = tid; j < 4 * 160; j += 256) {
                int ch = j / 160, i = j - ch * 160;
                int p = p0 + i;
                float v = (i < 154 && p >= 0 && p < XLEN) ? xb[ch * XLEN + p] : 0.0f;
                xraw[ch * 160 + i] = f16rne(v);
            }
        }
    }
    __syncthreads();

    // 2. im2col via aligned b128 + funnel windows; k = ch*32+kk
#pragma unroll
    for (int i = 0; i < 8; ++i) {
        int j = i * 256 + tid;
        int r = j >> 4, kg = j & 15;
        int ch = kg >> 2, q = kg & 3;
        const unsigned short* chb = xraw + ch * 160;
        ushort8v o;
        if (q < 3) {
            o = lds_window8(chb, r + q * 8);
        } else {
            o = (ushort8v){chb[r + 24], chb[r + 25], 0, 0, 0, 0, 0, 0};
        }
        *reinterpret_cast<ushort8v*>(As + r * AST + kg * 8) = o;
    }
    __syncthreads();

    // 3. MFMA: 4 k-steps, B ping-pong prefetch
    f32x4 acc[4][4];
#pragma unroll
    for (int m = 0; m < 4; ++m)
#pragma unroll
        for (int n = 0; n < 4; ++n) acc[m][n] = (f32x4){0.f, 0.f, 0.f, 0.f};

#pragma unroll
    for (int ks = 0; ks < 4; ++ks) {
        const ushort8v* bcur = (ks & 1) ? bB : bA;
        ushort8v* bnext = (ks & 1) ? bA : bB;
        if (ks < 3) {
#pragma unroll
            for (int n = 0; n < 4; ++n) {
                int cg = col0 + wc * 64 + n * 16 + l15;
                cg = min(cg, COUT - 1);
                bnext[n] = *reinterpret_cast<const ushort8v*>(
                    wd + (size_t)cg * 128 + (ks + 1) * 32 + lq * 8);
            }
        }
        half8v af[4];
#pragma unroll
        for (int m = 0; m < 4; ++m)
            af[m] = *reinterpret_cast<const half8v*>(As + (wr * 64 + m * 16 + l15) * AST + ks * 32 + lq * 8);
#pragma unroll
        for (int m = 0; m < 4; ++m)
#pragma unroll
            for (int n = 0; n < 4; ++n)
                acc[m][n] = __builtin_amdgcn_mfma_f32_16x16x32_f16(
                    af[m], *reinterpret_cast<const half8v*>(&bcur[n]), acc[m][n], 0, 0, 0);
    }
    __syncthreads();   // As dead; Csh aliases it

    float pu4 = -1.0e30f;

    // 4a. wr=0 waves write C rows 0..63
    if (wr == 0) {
#pragma unroll
        for (int m = 0; m < 4; ++m)
#pragma unroll
            for (int n = 0; n < 4; ++n)
#pragma unroll
                for (int rg = 0; rg < 4; ++rg) {
                    int row = m * 16 + lq * 4 + rg;
                    int col = wc * 64 + n * 16 + l15;
                    Csh[row * CST + col] = acc[m][n][rg];
                }
    }
    __syncthreads();

    // 4b. pool u=0..3 + partial u=4
#pragma unroll
    for (int i = 0; i < 2; ++i) {
        int j = i * 256 + tid;
        int u = j >> 7, c = j & 127;
        int cg = col0 + c;
        float mx = -1.0e30f;
        if (wt == 0) {
#pragma unroll
            for (int jj = 0; jj < 13; ++jj) {
                int r = 13 * u + jj;
                if (r >= 14) mx = fmaxf(mx, Csh[r * CST + c]);
            }
        } else {
#pragma unroll
            for (int jj = 0; jj < 13; ++jj) {
                int r = 13 * u + jj;
                mx = fmaxf(mx, Csh[r * CST + c]);
            }
        }
        if (cg < COUT) {
            float v = fmaxf(mx + cb[cg], 0.0f);
            seqs[((size_t)(wt * 9 + u) * BB + b) * 320 + cg] = f16rne(v);
        }
    }
    if (tid < 128) {
        int c = tid;
#pragma unroll
        for (int jj = 0; jj < 12; ++jj) pu4 = fmaxf(pu4, Csh[(52 + jj) * CST + c]);
    }
    __syncthreads();

    // 5a. wr=1 waves write C rows 64..127
    if (wr == 1) {
#pragma unroll
        for (int m = 0; m < 4; ++m)
#pragma unroll
            for (int n = 0; n < 4; ++n)
#pragma unroll
                for (int rg = 0; rg < 4; ++rg) {
                    int row = m * 16 + lq * 4 + rg;
                    int col = wc * 64 + n * 16 + l15;
                    Csh[row * CST + col] = acc[m][n][rg];
                }
    }
    __syncthreads();

    // 5b. pool u=5..8 + finish u=4
#pragma unroll
    for (int i = 0; i < 2; ++i) {
        int j = i * 256 + tid;
        int u = 5 + (j >> 7), c = j & 127;
        int cg = col0 + c;
        float mx = -1.0e30f;
#pragma unroll
        for (int jj = 0; jj < 13; ++jj) {
            int r = 13 * u + jj;
            mx = fmaxf(mx, Csh[(r - 64) * CST + c]);
        }
        if (cg < COUT) {
            float v = fmaxf(mx + cb[cg], 0.0f);
            seqs[((size_t)(wt * 9 + u) * BB + b) * 320 + cg] = f16rne(v);
        }
    }
    if (tid < 128) {
        int c = tid;
        int cg = col0 + c;
        pu4 = fmaxf(pu4, Csh[0 * CST + c]);
        if (cg < COUT) {
            float v = fmaxf(pu4 + cb[cg], 0.0f);
            seqs[((size_t)(wt * 9 + 4) * BB + b) * 320 + cg] = f16rne(v);
        }
    }
}

// ---------------------------------------------------------------------------
// gemm2: single-pass f16 GEMM. out[r][n] = sum_k f16(A[r][k]) * f16(B[n][k]).
// BF32: B loaded as f32 from global, converted f16 during staging.
// VAR 0 = LSTM (A = seqs f16, epilogue -> h f16, XCD grid; B pre-permuted f16)
// VAR 1 = gene (A f32 -> f16; B = gene_w f32, split-K 24, XCD-pinned sp)
// VAR 2 = lin  (A = attn*h f16; B = lin_w f32, split-K 8)
// ---------------------------------------------------------------------------
template <int VAR, bool BF32>
__global__ __launch_bounds__(256) void gemm2(const unsigned short* __restrict__ Apre,
                                             const float* __restrict__ Af32, int lda,
                                             const unsigned short* __restrict__ Bn,
                                             const float* __restrict__ Bf32, int ldb,
                                             const float* __restrict__ attnp,
                                             int M, int N, int Kreal,
                                             int totChunks, int cps,
                                             float* __restrict__ outp,
                                             const float* __restrict__ biasv,
                                             unsigned short* __restrict__ hout) {
    __shared__ unsigned short Al[128][72];
    __shared__ unsigned short Bl[128][72];
    const int tid = threadIdx.x;

    int bm, bn, sp;
    if (VAR == 0) {
        int xcd = blockIdx.x;
        bn = blockIdx.y % 10;
        bm = xcd + 8 * (blockIdx.y / 10);
        sp = 0;
        if (bm >= 282) return;
    } else if (VAR == 1) {
        int xcd = blockIdx.x;
        sp = xcd + 8 * (blockIdx.y / 21);
        int r = blockIdx.y % 21;
        bm = r / 3; bn = r % 3;
    } else {
        sp = blockIdx.x;
        bn = blockIdx.y / 7; bm = blockIdx.y % 7;
    }
    const int row0 = bm * 128, col0 = bn * 128;
    const int c_beg = sp * cps;
    const int c_end = min(totChunks, c_beg + cps);

    const int w = tid >> 6, lane = tid & 63;
    const int wr = w >> 1, wc = w & 1;
    const int l15 = lane & 15, lq = lane >> 4;

    f32x4 acc[4][4];
#pragma unroll
    for (int m = 0; m < 4; ++m)
#pragma unroll
        for (int n = 0; n < 4; ++n) acc[m][n] = (f32x4){0.f, 0.f, 0.f, 0.f};

    ushort8v aP[4];      // VAR0 raw seqs, VAR2 raw h
    float4 aF[8];        // VAR1 raw f32
    float aW[4];         // VAR2 attn weights
    ushort8v bP[4];      // !BF32
    float4 bF[8];        // BF32 raw f32

    auto loadA = [&](int c) {
        int k0 = c * 64;
        if (VAR == 0) {
#pragma unroll
            for (int i = 0; i < 4; ++i) {
                int j = tid + i * 256;
                int r = j >> 3, kg = j & 7;
                int gr = row0 + r;
                ushort8v z = {0, 0, 0, 0, 0, 0, 0, 0};
                if (gr < M) z = *reinterpret_cast<const ushort8v*>(
                    Apre + (size_t)gr * 320 + k0 + kg * 8);
                aP[i] = z;
            }
        } else if (VAR == 1) {
            bool fast = (k0 + 64 <= Kreal);
#pragma unroll
            for (int i = 0; i < 4; ++i) {
                int j = tid + i * 256;
                int r = j >> 3, kg = j & 7;
                int gr = row0 + r;
                float4 v0 = make_float4(0.f, 0.f, 0.f, 0.f);
                float4 v1 = make_float4(0.f, 0.f, 0.f, 0.f);
                if (gr < M) {
                    int kb = k0 + kg * 8;
                    const float* p = Af32 + (size_t)gr * lda + kb;
                    if (fast) {
                        v0 = *reinterpret_cast<const float4*>(p);
                        v1 = *reinterpret_cast<const float4*>(p + 4);
                    } else {
                        if (kb + 0 < Kreal) v0.x = p[0];
                        if (kb + 1 < Kreal) v0.y = p[1];
                        if (kb + 2 < Kreal) v0.z = p[2];
                        if (kb + 3 < Kreal) v0.w = p[3];
                        if (kb + 4 < Kreal) v1.x = p[4];
                        if (kb + 5 < Kreal) v1.y = p[5];
                        if (kb + 6 < Kreal) v1.z = p[6];
                        if (kb + 7 < Kreal) v1.w = p[7];
                    }
                }
                aF[2 * i] = v0; aF[2 * i + 1] = v1;
            }
        } else {
            int t = k0 / 320, d0 = k0 - t * 320;
#pragma unroll
            for (int i = 0; i < 4; ++i) {
                int j = tid + i * 256;
                int r = j >> 3, kg = j & 7;
                int gr = row0 + r;
                ushort8v z = {0, 0, 0, 0, 0, 0, 0, 0};
                float aw = 0.0f;
                if (gr < M) {
                    z = *reinterpret_cast<const ushort8v*>(
                        Apre + ((size_t)t * BB + gr) * 320 + d0 + kg * 8);
                    aw = attnp[t * BB + gr];
                }
                aP[i] = z; aW[i] = aw;
            }
        }
    };
    auto loadB = [&](int c) {
        int k0 = c * 64;
        if (BF32) {
            bool fast = (k0 + 64 <= Kreal);
#pragma unroll
            for (int i = 0; i < 4; ++i) {
                int j = tid + i * 256;
                int r = j >> 3, kg = j & 7;
                int gc = col0 + r;
                float4 v0 = make_float4(0.f, 0.f, 0.f, 0.f);
                float4 v1 = make_float4(0.f, 0.f, 0.f, 0.f);
                if (gc < N) {
                    int kb = k0 + kg * 8;
                    const float* p = Bf32 + (size_t)gc * ldb + kb;
                    if (fast) {
                        v0 = *reinterpret_cast<const float4*>(p);
                        v1 = *reinterpret_cast<const float4*>(p + 4);
                    } else {
                        if (kb + 0 < Kreal) v0.x = p[0];
                        if (kb + 1 < Kreal) v0.y = p[1];
                        if (kb + 2 < Kreal) v0.z = p[2];
                        if (kb + 3 < Kreal) v0.w = p[3];
                        if (kb + 4 < Kreal) v1.x = p[4];
                        if (kb + 5 < Kreal) v1.y = p[5];
                        if (kb + 6 < Kreal) v1.z = p[6];
                        if (kb + 7 < Kreal) v1.w = p[7];
                    }
                }
                bF[2 * i] = v0; bF[2 * i + 1] = v1;
            }
        } else {
#pragma unroll
            for (int i = 0; i < 4; ++i) {
                int j = tid + i * 256;
                int r = j >> 3, sg = j & 7;
                int gc = col0 + r;
                ushort8v z = {0, 0, 0, 0, 0, 0, 0, 0};
                if (gc < N) z = *reinterpret_cast<const ushort8v*>(Bn + (size_t)gc * ldb + k0 + sg * 8);
                bP[i] = z;
            }
        }
    };
    auto writeAB = [&]() {
        if (VAR == 0) {
#pragma unroll
            for (int i = 0; i < 4; ++i) {
                int j = tid + i * 256;
                int r = j >> 3, kg = j & 7;
                *reinterpret_cast<ushort8v*>(&Al[r][kg * 8]) = aP[i];
            }
        } else {
#pragma unroll
            for (int i = 0; i < 4; ++i) {
                int j = tid + i * 256;
                int r = j >> 3, kg = j & 7;
                ushort8v hv;
                if (VAR == 1) {
                    hv[0] = f16rne(aF[2 * i].x); hv[1] = f16rne(aF[2 * i].y);
                    hv[2] = f16rne(aF[2 * i].z); hv[3] = f16rne(aF[2 * i].w);
                    hv[4] = f16rne(aF[2 * i + 1].x); hv[5] = f16rne(aF[2 * i + 1].y);
                    hv[6] = f16rne(aF[2 * i + 1].z); hv[7] = f16rne(aF[2 * i + 1].w);
                } else {
#pragma unroll
                    for (int e = 0; e < 8; ++e) hv[e] = f16rne(f16tof(aP[i][e]) * aW[i]);
                }
                *reinterpret_cast<ushort8v*>(&Al[r][kg * 8]) = hv;
            }
        }
        if (BF32) {
#pragma unroll
            for (int i = 0; i < 4; ++i) {
                int j = tid + i * 256;
                int r = j >> 3, kg = j & 7;
                ushort8v hv;
                hv[0] = f16rne(bF[2 * i].x); hv[1] = f16rne(bF[2 * i].y);
                hv[2] = f16rne(bF[2 * i].z); hv[3] = f16rne(bF[2 * i].w);
                hv[4] = f16rne(bF[2 * i + 1].x); hv[5] = f16rne(bF[2 * i + 1].y);
                hv[6] = f16rne(bF[2 * i + 1].z); hv[7] = f16rne(bF[2 * i + 1].w);
                *reinterpret_cast<ushort8v*>(&Bl[r][kg * 8]) = hv;
            }
        } else {
#pragma unroll
            for (int i = 0; i < 4; ++i) {
                int j = tid + i * 256;
                int r = j >> 3, sg = j & 7;
                *reinterpret_cast<ushort8v*>(&Bl[r][sg * 8]) = bP[i];
            }
        }
    };

    loadA(c_beg); loadB(c_beg);

    for (int c = c_beg; c < c_end; ++c) {
        __syncthreads();
        writeAB();
        __syncthreads();
        if (c + 1 < c_end) { loadA(c + 1); loadB(c + 1); }

#pragma unroll
        for (int ks = 0; ks < 2; ++ks) {
            half8v bf[4];
#pragma unroll
            for (int n = 0; n < 4; ++n)
                bf[n] = *reinterpret_cast<const half8v*>(&Bl[wc * 64 + n * 16 + l15][ks * 32 + lq * 8]);
            half8v af[4];
#pragma unroll
            for (int m = 0; m < 4; ++m)
                af[m] = *reinterpret_cast<const half8v*>(&Al[wr * 64 + m * 16 + l15][ks * 32 + lq * 8]);
#pragma unroll
            for (int m = 0; m < 4; ++m)
#pragma unroll
                for (int n = 0; n < 4; ++n)
                    acc[m][n] = __builtin_amdgcn_mfma_f32_16x16x32_f16(af[m], bf[n], acc[m][n], 0, 0, 0);
        }
    }

    if (VAR != 0) {
#pragma unroll
        for (int m = 0; m < 4; ++m)
#pragma unroll
            for (int n = 0; n < 4; ++n)
#pragma unroll
                for (int rg = 0; rg < 4; ++rg) {
                    int row_g = row0 + wr * 64 + m * 16 + lq * 4 + rg;
                    int col_g = col0 + wc * 64 + n * 16 + l15;
                    if (row_g < M && col_g < N)
                        outp[((size_t)sp * M + row_g) * N + col_g] = acc[m][n][rg];
                }
    } else {
        int c0 = col0 + wc * 64;
        int dir = c0 / 640;
        int jgl = (c0 % 640) >> 6;
        int hcol = dir * HID + jgl * 16 + l15;
        float bi = biasv[c0 + l15];
        float bg = biasv[c0 + 32 + l15];
        float bo = biasv[c0 + 48 + l15];
#pragma unroll
        for (int m = 0; m < 4; ++m)
#pragma unroll
            for (int rg = 0; rg < 4; ++rg) {
                int row_g = row0 + wr * 64 + m * 16 + lq * 4 + rg;
                if (row_g >= M) continue;
                float gi = acc[m][0][rg] + bi;
                float gg = acc[m][2][rg] + bg;
                float go = acc[m][3][rg] + bo;
                float cc = sigf(gi) * tanhfast(gg);
                hout[(size_t)row_g * 320 + hcol] = f16rne(sigf(go) * tanhfast(cc));
            }
    }
}

// ---------------------------------------------------------------------------
__global__ void gene_reduce_kernel(const float* __restrict__ part, const float* __restrict__ gene_b,
                                   float* __restrict__ out) {
    int idx = blockIdx.x * 256 + threadIdx.x;
    if (idx >= BB * GENE_N) return;
    int n = idx % GENE_N;
    float sum = gene_b[n];
#pragma unroll
    for (int ss = 0; ss < GENE_SPLITS; ++ss) sum += part[(size_t)ss * (BB * GENE_N) + idx];
    out[idx] = sum;
}

__global__ void bn_stats_kernel(const float* __restrict__ g, float* __restrict__ stats) {
    int n = blockIdx.x;
    int tid = threadIdx.x;
    float s = 0.0f, s2 = 0.0f;
    for (int m = tid; m < BB; m += 256) {
        float v = g[(size_t)m * GENE_N + n];
        s += v; s2 += v * v;
    }
    __shared__ float red0[256], red1[256];
    red0[tid] = s; red1[tid] = s2;
    __syncthreads();
    for (int off = 128; off; off >>= 1) {
        if (tid < off) { red0[tid] += red0[tid + off]; red1[tid] += red1[tid + off]; }
        __syncthreads();
    }
    if (tid == 0) {
        float mean = red0[0] / (float)BB;
        float var = red1[0] / (float)BB - mean * mean;
        stats[n] = mean;
        stats[GENE_N + n] = rsqrtf(var + 1e-5f);
    }
}

// attn with BN-normalize + ReLU fused; 4 rows per 256-thread block.
__global__ void attn_kernel(const unsigned short* __restrict__ h, const float* __restrict__ graw,
                            const float* __restrict__ stats,
                            const float* __restrict__ gamma, const float* __restrict__ beta,
                            float* __restrict__ attn) {
    int r = blockIdx.x * 4 + (threadIdx.x >> 6);
    int b = r % BB;
    int lane = threadIdx.x & 63;
    const unsigned short* hr = h + (size_t)r * 320;
    const float* gr = graw + (size_t)b * 320;
    float s = 0.0f;
    for (int d = lane; d < 320; d += 64) {
        float gv = (gr[d] - stats[d]) * stats[GENE_N + d] * gamma[d] + beta[d];
        gv = fmaxf(gv, 0.0f);
        s += f16tof(hr[d]) * gv;
    }
    for (int off = 32; off; off >>= 1) s += __shfl_down(s, off);
    if (lane == 0) attn[r] = s;
}

__global__ void lin_reduce_kernel(const float* __restrict__ part, const float* __restrict__ lin_b,
                                  float* __restrict__ hid) {
    int idx = blockIdx.x * 256 + threadIdx.x;
    if (idx >= BB * LIN_N) return;
    int n = idx % LIN_N;
    float sum = lin_b[n];
#pragma unroll
    for (int ss = 0; ss < LIN_SPLITS; ++ss) sum += part[(size_t)ss * (BB * LIN_N) + idx];
    hid[idx] = fmaxf(sum, 0.0f);
}

__global__ void out_kernel(const float* __restrict__ hid, const float* __restrict__ ow,
                           const float* __restrict__ ob, float* __restrict__ out) {
    int b = blockIdx.x;
    int lane = threadIdx.x;
    float s = 0.0f;
    for (int n = lane; n < LIN_N; n += 64) s += hid[(size_t)b * LIN_N + n] * ow[n];
    for (int off = 32; off; off >>= 1) s += __shfl_down(s, off);
    if (lane == 0) out[b] = s + ob[0];
}

// ---------------------------------------------------------------------------
extern "C" void kernel_launch(void* const* d_in, const int* in_sizes, int n_in,
                              void* d_out, int out_size, void* d_ws, size_t ws_size,
                              hipStream_t stream) {
    const float* x        = (const float*)d_in[0];
    const float* geneexpr = (const float*)d_in[1];
    const float* conv_w   = (const float*)d_in[2];
    const float* conv_b   = (const float*)d_in[3];
    const float* w_ih_f   = (const float*)d_in[4];
    const float* b_ih_f   = (const float*)d_in[5];
    const float* b_hh_f   = (const float*)d_in[6];
    const float* w_ih_b   = (const float*)d_in[7];
    const float* b_ih_b   = (const float*)d_in[8];
    const float* b_hh_b   = (const float*)d_in[9];
    const float* gene_w   = (const float*)d_in[10];
    const float* gene_b   = (const float*)d_in[11];
    const float* bn_gamma = (const float*)d_in[12];
    const float* bn_beta  = (const float*)d_in[13];
    const float* lin_w    = (const float*)d_in[14];
    const float* lin_b    = (const float*)d_in[15];
    const float* out_w    = (const float*)d_in[16];
    const float* out_b    = (const float*)d_in[17];

    float* ws  = (float*)d_ws;
    float* out = (float*)d_out;

    unsigned short* h     = (unsigned short*)(ws + OFF_H);
    unsigned short* Bp    = (unsigned short*)(ws + OFF_BP);
    float* biasv          = ws + OFF_BIAS;
    unsigned short* wd    = (unsigned short*)(ws + OFF_WD);
    float* gene           = ws + OFF_GENE;
    float* stats          = ws + OFF_STATS;
    float* attn           = ws + OFF_ATTN;
    float* hid            = ws + OFF_HID;
    float* gpart          = ws + OFF_SCR;
    float* lpart          = ws + OFF_SCR;
    unsigned short* seqs  = (unsigned short*)(ws + OFF_SEQS);

    // 1. weight preps (LSTM permute + conv pad only)
    prep_lstm_kernel<<<1600, 256, 0, stream>>>(w_ih_f, b_ih_f, b_hh_f,
                                               w_ih_b, b_ih_b, b_hh_b, Bp, biasv);
    prep_convw_kernel<<<160, 256, 0, stream>>>(conv_w, wd);
    // 2. fused conv -> seqs f16
    conv_mfma_kernel<<<dim3(BB * 5, 3, 1), 256, 0, stream>>>(x, wd, conv_b, seqs);
    // 3. LSTM GEMM (XCD-pinned bm) -> h f16
    gemm2<0, false><<<dim3(8, 360), 256, 0, stream>>>(
        seqs, nullptr, 0, Bp, nullptr, LSTM_K, nullptr,
        LSTM_M, LSTM_N, LSTM_K, 5, 5, nullptr, biasv, h);
    // 4. gene GEMM (split-K 24, XCD-pinned sp; B = gene_w f32 direct)
    gemm2<1, true><<<dim3(8, 63), 256, 0, stream>>>(
        nullptr, geneexpr, GENE_K, nullptr, gene_w, GENE_K, nullptr,
        BB, GENE_N, GENE_K, 310, 13, gpart, nullptr, nullptr);
    // 5. reduce + bias
    gene_reduce_kernel<<<1000, 256, 0, stream>>>(gpart, gene_b, gene);
    // 6. BN stats
    bn_stats_kernel<<<GENE_N, 256, 0, stream>>>(gene, stats);
    // 7. attention scores (BN apply fused)
    attn_kernel<<<9000, 256, 0, stream>>>(h, gene, stats, bn_gamma, bn_beta, attn);
    // 8. lin GEMM (split-K 8 = XCD; A = attn*h, B = lin_w f32 direct)
    gemm2<2, true><<<dim3(8, 56), 256, 0, stream>>>(
        h, nullptr, 0, nullptr, lin_w, LIN_K, attn,
        BB, LIN_N, LIN_K, 225, 29, lpart, nullptr, nullptr);
    // 9. reduce + bias + relu
    lin_reduce_kernel<<<2891, 256, 0, stream>>>(lpart, lin_b, hid);
    // 10. final dot
    out_kernel<<<BB, 64, 0, stream>>>(hid, out_w, out_b, out);
}